// Round 7
// baseline (2285.953 us; speedup 1.0000x reference)
//
#include <hip/hip_runtime.h>
#include <hip/hip_bf16.h>

#define N_TOK 8192
#define DDIM 1024
#define HDIM 4096
#define NEXP 8
#define TOPK 2
#define NK (N_TOK*TOPK)
#define BM 256
#define BK 32
#define MAXT 72    // 16384/256 + 8 pad tiles

typedef __hip_bfloat16 bf16;
typedef __attribute__((ext_vector_type(8))) short bf16x8;
typedef __attribute__((ext_vector_type(4))) float f32x4;

__device__ __forceinline__ void gload16(const void* g, void* lds) {
  auto l = (__attribute__((address_space(3))) unsigned int*)(unsigned int)(unsigned long long)lds;
  auto gg = (const __attribute__((address_space(1))) unsigned int*)(unsigned long long)g;
  __builtin_amdgcn_global_load_lds(gg, l, 16, 0, 0);
}

// ---- router ----
__global__ void k_detect(const int* __restrict__ idx, int* __restrict__ flag) {
  if (threadIdx.x == 0 && blockIdx.x == 0) {
    int allz = 1;
    for (int i = 1; i < 32; i += 2) allz &= (idx[i] == 0);
    *flag = allz ? 2 : 1;   // 2 => int64 little-endian, 1 => int32
  }
}

__global__ void k_count(const int* __restrict__ idx, const int* __restrict__ flag,
                        int* __restrict__ cnt) {
  int r = blockIdx.x * blockDim.x + threadIdx.x;
  if (r >= NK) return;
  int s = *flag;
  int e = idx[r * s];
  e = min(max(e, 0), NEXP - 1);
  atomicAdd(&cnt[e], 1);
}

__global__ void k_scan(const int* __restrict__ cnt, int* __restrict__ offp,
                       int* __restrict__ off2, int* __restrict__ texp,
                       int* __restrict__ tok) {
  __shared__ int so[NEXP + 1], sc[NEXP];
  int tid = threadIdx.x;
  if (tid == 0) {
    int cum = 0;
    for (int e = 0; e < NEXP; e++) {
      so[e] = cum; sc[e] = cnt[e];
      cum += ((cnt[e] + BM - 1) / BM) * BM;
    }
    so[NEXP] = cum;
    for (int e = 0; e <= NEXP; e++) offp[e] = so[e];
  }
  __syncthreads();
  if (tid < NEXP) off2[tid] = so[tid];
  int total_tiles = so[NEXP] / BM;
  for (int t = tid; t < MAXT; t += blockDim.x) {
    int e = -1;
    if (t < total_tiles) {
      for (int q = 0; q < NEXP; q++)
        if (t * BM >= so[q] && t * BM < so[q + 1]) e = q;
    }
    texp[t] = e;
  }
  for (int e = 0; e < NEXP; e++) {
    int start = so[e] + sc[e], end = so[e + 1];
    for (int i = start + tid; i < end; i += blockDim.x) tok[i] = 0;
  }
}

__global__ void k_scatter(const int* __restrict__ idx, const int* __restrict__ flag,
                          int* __restrict__ off2, int* __restrict__ tok,
                          int* __restrict__ pos) {
  int r = blockIdx.x * blockDim.x + threadIdx.x;
  if (r >= NK) return;
  int s = *flag;
  int e = idx[r * s];
  e = min(max(e, 0), NEXP - 1);
  int p = atomicAdd(&off2[e], 1);
  tok[p] = r >> 1;
  pos[r] = p;
}

// ---- gather + fp32->bf16: Xg[p][:] = bf16(x[tok[p]][:]) ----
__global__ void k_gather(const float* __restrict__ x, const int* __restrict__ tok,
                         const int* __restrict__ offp, bf16* __restrict__ xg) {
  int rows = offp[NEXP];
  int chunks = rows * (DDIM / 8);
  int stride = gridDim.x * blockDim.x;
  for (int i = blockIdx.x * blockDim.x + threadIdx.x; i < chunks; i += stride) {
    int p = i >> 7;            // DDIM/8 = 128
    int c = i & 127;
    int r = tok[p];
    float4 a = ((const float4*)x)[((size_t)r * DDIM + c * 8) / 4];
    float4 b = ((const float4*)x)[((size_t)r * DDIM + c * 8) / 4 + 1];
    union { bf16 h[8]; uint4 v; } u;
    u.h[0] = __float2bfloat16(a.x); u.h[1] = __float2bfloat16(a.y);
    u.h[2] = __float2bfloat16(a.z); u.h[3] = __float2bfloat16(a.w);
    u.h[4] = __float2bfloat16(b.x); u.h[5] = __float2bfloat16(b.y);
    u.h[6] = __float2bfloat16(b.z); u.h[7] = __float2bfloat16(b.w);
    *(uint4*)&xg[(size_t)p * DDIM + c * 8] = u.v;
  }
}

// [E][R][C] fp32 -> [E][C][R] bf16, ushort2 stores
__global__ void k_transpose(const float* __restrict__ in, bf16* __restrict__ out,
                            int R, int C) {
  __shared__ float t[32][33];
  size_t ebase = (size_t)blockIdx.z * R * C;
  int tx = threadIdx.x & 31, ty = threadIdx.x >> 5;
  int c0 = blockIdx.x * 32, r0 = blockIdx.y * 32;
#pragma unroll
  for (int j = 0; j < 4; j++)
    t[ty + j * 8][tx] = in[ebase + (size_t)(r0 + ty + j * 8) * C + c0 + tx];
  __syncthreads();
  int tx2 = (threadIdx.x & 15) * 2;
  int cy  = threadIdx.x >> 4;
#pragma unroll
  for (int p = 0; p < 2; p++) {
    int c = cy + p * 16;
    union { bf16 h[2]; unsigned int u; } w;
    w.h[0] = __float2bfloat16(t[tx2][c]);
    w.h[1] = __float2bfloat16(t[tx2 + 1][c]);
    *(unsigned int*)&out[ebase + (size_t)(c0 + c) * R + r0 + tx2] = w.u;
  }
}

// ---- grouped GEMM, minimal 2-phase, BK=32, 2+ blocks/CU ----
// MODE 0: Xg @ W1t -> hbuf bf16 (+bias, ReLU). 256x256 tile, wave 128x64.
// MODE 1: hbuf @ W2t -> ybuf bf16 (+bias).    256x128 tile, wave 128x32.
template<int MODE>
__global__ __launch_bounds__(512, 4) void k_gemm(
    const bf16* __restrict__ A, const bf16* __restrict__ Bt,
    const float* __restrict__ bias, const int* __restrict__ texp,
    int tile_base, void* __restrict__ Cout)
{
  constexpr int KT   = MODE ? HDIM : DDIM;   // 4096 : 1024
  constexpr int NCOL = MODE ? DDIM : HDIM;
  constexpr int BN   = MODE ? 128 : 256;
  constexpr int GX   = NCOL / BN;            // 8 : 16
  constexpr int NT   = KT / BK;              // 128 : 32
  constexpr int NI   = BN / 64;              // 2 : 4  (16-col frags per wave quadrant)
  constexpr int NBIT = MODE ? 1 : 2;         // B staging instrs per thread
  constexpr int ABYT = BM * BK * 2;          // 16384
  constexpr int BUFB = (BM + BN) * BK * 2;   // 24576 : 32768

  // bijective XCD-aware swizzle (m204)
  int nwg = gridDim.x, orig = blockIdx.x;
  int q8 = nwg >> 3, r8 = nwg & 7;
  int xcd = orig & 7, jj0 = orig >> 3;
  int w = (xcd < r8 ? xcd * (q8 + 1) : r8 * (q8 + 1) + (xcd - r8) * q8) + jj0;
  int tn = w % GX;
  int tmr = w / GX;
  int tm = tile_base + tmr;
  int e = texp[tm];
  if (e < 0) return;

  int tid = threadIdx.x, lane = tid & 63, wid = tid >> 6;
  int wm = wid >> 2, wn = wid & 3;           // 2M x 4N
  int lr = lane & 15, kg = lane >> 4;

  __shared__ __align__(16) char lds[2 * BUFB];   // 48 or 64 KiB

  // per-thread staging source offsets (elements), source-side chunk swizzle
  int sidx = tid, srow = sidx >> 2, sc = sidx & 3;
  int scs = (sc ^ ((srow >> 1) & 3)) * 8;
  int arow0 = (MODE ? tmr : tm) * BM;
  unsigned aoff[2], boff[NBIT];
#pragma unroll
  for (int it = 0; it < 2; ++it) {
    int idx = it * 512 + tid, row = idx >> 2, c = idx & 3;
    aoff[it] = (unsigned)((arow0 + row) * KT + (c ^ ((row >> 1) & 3)) * 8);
  }
#pragma unroll
  for (int it = 0; it < NBIT; ++it) {
    int idx = it * 512 + tid, row = idx >> 2, c = idx & 3;
    boff[it] = (unsigned)((e * NCOL + tn * BN + row) * KT + (c ^ ((row >> 1) & 3)) * 8);
  }

  auto stage = [&](int kt, int par) {
    char* base = lds + par * BUFB;
#pragma unroll
    for (int it = 0; it < 2; ++it)
      gload16(A + aoff[it] + kt * BK, base + (it * 512 + tid) * 16);
#pragma unroll
    for (int it = 0; it < NBIT; ++it)
      gload16(Bt + boff[it] + kt * BK, base + ABYT + (it * 512 + tid) * 16);
  };

  f32x4 acc[8][NI];
#pragma unroll
  for (int i = 0; i < 8; i++)
#pragma unroll
    for (int j = 0; j < NI; j++) acc[i][j] = (f32x4){0.f, 0.f, 0.f, 0.f};

  // prologue
  stage(0, 0);
  asm volatile("s_waitcnt vmcnt(0)" ::: "memory");
  __syncthreads();

  int par = 0;
#pragma unroll 1
  for (int kt = 0; kt < NT; ++kt) {
    if (kt + 1 < NT) stage(kt + 1, par ^ 1);

    const char* base = lds + par * BUFB;
    bf16x8 av[8], bv[NI];
#pragma unroll
    for (int mi = 0; mi < 8; ++mi) {
      int m = wm * 128 + mi * 16 + lr;
      av[mi] = *(const bf16x8*)(base + (m * 4 + (kg ^ ((m >> 1) & 3))) * 16);
    }
#pragma unroll
    for (int ni = 0; ni < NI; ++ni) {
      int n = wn * (BN / 4) + ni * 16 + lr;
      bv[ni] = *(const bf16x8*)(base + ABYT + (n * 4 + (kg ^ ((n >> 1) & 3))) * 16);
    }
    __builtin_amdgcn_s_setprio(1);
#pragma unroll
    for (int mi = 0; mi < 8; ++mi)
#pragma unroll
      for (int ni = 0; ni < NI; ++ni)
        acc[mi][ni] = __builtin_amdgcn_mfma_f32_16x16x32_bf16(
            av[mi], bv[ni], acc[mi][ni], 0, 0, 0);
    __builtin_amdgcn_s_setprio(0);

    if (kt + 1 < NT) {
      asm volatile("s_waitcnt vmcnt(0)" ::: "memory");
      __syncthreads();
      par ^= 1;
    }
  }

  // epilogue (C/D map m89)
  const float* be = bias + (size_t)e * NCOL;
  int crow0 = (MODE ? tm : tmr) * BM;   // MODE1 global rows, MODE0 slice-local
#pragma unroll
  for (int ni = 0; ni < NI; ++ni) {
    int n = tn * BN + wn * (BN / 4) + ni * 16 + lr;
    float bvv = be[n];
#pragma unroll
    for (int mi = 0; mi < 8; ++mi) {
#pragma unroll
      for (int j = 0; j < 4; j++) {
        int mrow = wm * 128 + mi * 16 + kg * 4 + j;
        float v = acc[mi][ni][j] + bvv;
        if (MODE == 0) v = fmaxf(v, 0.f);
        ((bf16*)Cout)[(size_t)(crow0 + mrow) * NCOL + n] = __float2bfloat16(v);
      }
    }
  }
}

// ---- combine (bf16 y) ----
__global__ void k_combine(const bf16* __restrict__ y, const float* __restrict__ prob,
                          const int* __restrict__ pos, float* __restrict__ out) {
  int gid = blockIdx.x * blockDim.x + threadIdx.x;  // over N*D/8
  if (gid >= N_TOK * DDIM / 8) return;
  int n = gid >> 7;          // DDIM/8 = 128
  int d8 = gid & 127;
  int r0 = pos[2 * n], r1 = pos[2 * n + 1];
  float p0 = prob[2 * n], p1 = prob[2 * n + 1];
  uint4 a = *(const uint4*)&y[(size_t)r0 * DDIM + d8 * 8];
  uint4 b = *(const uint4*)&y[(size_t)r1 * DDIM + d8 * 8];
  const unsigned short* ah = (const unsigned short*)&a;
  const unsigned short* bh = (const unsigned short*)&b;
  float o[8];
#pragma unroll
  for (int k = 0; k < 8; k++) {
    float fa = __uint_as_float((unsigned)ah[k] << 16);
    float fb = __uint_as_float((unsigned)bh[k] << 16);
    o[k] = p0 * fa + p1 * fb;
  }
  float4* op = (float4*)&out[(size_t)n * DDIM + d8 * 8];
  op[0] = (float4){o[0], o[1], o[2], o[3]};
  op[1] = (float4){o[4], o[5], o[6], o[7]};
  if (gid == 0) out[(size_t)N_TOK * DDIM] = 0.f;   // total_loss
}

extern "C" void kernel_launch(void* const* d_in, const int* in_sizes, int n_in,
                              void* d_out, int out_size, void* d_ws, size_t ws_size,
                              hipStream_t stream) {
  const float* x    = (const float*)d_in[0];
  const float* prob = (const float*)d_in[1];
  const int*   idx  = (const int*)d_in[2];
  const float* W1   = (const float*)d_in[3];
  const float* b1   = (const float*)d_in[4];
  const float* W2   = (const float*)d_in[5];
  const float* b2   = (const float*)d_in[6];
  float* out = (float*)d_out;

  char* ws = (char*)d_ws;
  size_t cur = 0;
  auto alloc = [&](size_t bytes) -> void* {
    cur = (cur + 255) & ~(size_t)255;
    void* p = ws + cur; cur += bytes; return p;
  };
  int* cnt   = (int*)alloc(NEXP * 4);
  int* offp  = (int*)alloc((NEXP + 1) * 4);
  int* off2  = (int*)alloc(NEXP * 4);
  int* flag  = (int*)alloc(4);
  int* texp  = (int*)alloc(MAXT * 4);
  int* tok   = (int*)alloc((size_t)MAXT * BM * 4);
  int* pos   = (int*)alloc((size_t)NK * 4);
  bf16* Xg   = (bf16*)alloc((size_t)MAXT * BM * DDIM * 2);
  bf16* W1t  = (bf16*)alloc((size_t)NEXP * HDIM * DDIM * 2);
  bf16* W2t  = (bf16*)alloc((size_t)NEXP * DDIM * HDIM * 2);
  bf16* ybuf = (bf16*)alloc((size_t)MAXT * BM * DDIM * 2);
  cur = (cur + 255) & ~(size_t)255;
  size_t h_off = cur;
  size_t h_avail = ws_size > h_off ? ws_size - h_off : 0;
  long long ts_ll = (long long)(h_avail / ((size_t)BM * HDIM * 2));
  int ts = (int)(ts_ll < 1 ? 1 : (ts_ll > MAXT ? MAXT : ts_ll));
  bf16* hbuf = (bf16*)(ws + h_off);

  hipMemsetAsync(cnt, 0, NEXP * 4, stream);
  k_detect<<<1, 64, 0, stream>>>(idx, flag);
  k_count<<<(NK + 255) / 256, 256, 0, stream>>>(idx, flag, cnt);
  k_scan<<<1, 256, 0, stream>>>(cnt, offp, off2, texp, tok);
  k_scatter<<<(NK + 255) / 256, 256, 0, stream>>>(idx, flag, off2, tok, pos);
  k_gather<<<2048, 256, 0, stream>>>(x, tok, offp, Xg);
  k_transpose<<<dim3(HDIM / 32, DDIM / 32, NEXP), 256, 0, stream>>>(W1, W1t, DDIM, HDIM);
  k_transpose<<<dim3(DDIM / 32, HDIM / 32, NEXP), 256, 0, stream>>>(W2, W2t, HDIM, DDIM);

  for (int base = 0; base < MAXT; base += ts) {
    int cnt_t = (MAXT - base < ts) ? (MAXT - base) : ts;
    k_gemm<0><<<dim3(cnt_t * (HDIM / 256)), 512, 0, stream>>>(
        Xg, W1t, b1, texp, base, (void*)hbuf);
    k_gemm<1><<<dim3(cnt_t * (DDIM / 128)), 512, 0, stream>>>(
        hbuf, W2t, b2, texp, base, (void*)ybuf);
  }
  k_combine<<<(N_TOK * DDIM / 8 + 255) / 256, 256, 0, stream>>>(ybuf, prob, pos, out);
}

// Round 8
// 629.873 us; speedup vs baseline: 3.6292x; 3.6292x over previous
//
#include <hip/hip_runtime.h>
#include <hip/hip_bf16.h>

#define N_TOK 8192
#define DDIM 1024
#define HDIM 4096
#define NEXP 8
#define TOPK 2
#define NK (N_TOK*TOPK)
#define BM 128
#define BK 32
#define MAXT 136   // 16384/128 + 8 pad tiles

typedef __hip_bfloat16 bf16;
typedef __attribute__((ext_vector_type(8))) short bf16x8;
typedef __attribute__((ext_vector_type(4))) float f32x4;

__device__ __forceinline__ void gload16(const void* g, void* lds) {
  auto l = (__attribute__((address_space(3))) unsigned int*)(unsigned int)(unsigned long long)lds;
  auto gg = (const __attribute__((address_space(1))) unsigned int*)(unsigned long long)g;
  __builtin_amdgcn_global_load_lds(gg, l, 16, 0, 0);
}

// ---- router ----
__global__ void k_count(const int* __restrict__ idx, int stride,
                        int* __restrict__ cnt) {
  int r = blockIdx.x * blockDim.x + threadIdx.x;
  if (r >= NK) return;
  int e = idx[r * stride];
  e = min(max(e, 0), NEXP - 1);
  atomicAdd(&cnt[e], 1);
}

__global__ void k_scan(const int* __restrict__ cnt, int* __restrict__ offp,
                       int* __restrict__ off2, int* __restrict__ texp,
                       int* __restrict__ tok) {
  __shared__ int so[NEXP + 1], sc[NEXP];
  int tid = threadIdx.x;
  if (tid == 0) {
    int cum = 0;
    for (int e = 0; e < NEXP; e++) {
      so[e] = cum; sc[e] = cnt[e];
      cum += ((cnt[e] + BM - 1) / BM) * BM;
    }
    so[NEXP] = cum;
    for (int e = 0; e <= NEXP; e++) offp[e] = so[e];
  }
  __syncthreads();
  if (tid < NEXP) off2[tid] = so[tid];
  int total_tiles = so[NEXP] / BM;
  for (int t = tid; t < MAXT; t += blockDim.x) {
    int e = -1;
    if (t < total_tiles) {
      for (int q = 0; q < NEXP; q++)
        if (t * BM >= so[q] && t * BM < so[q + 1]) e = q;
    }
    texp[t] = e;
  }
  for (int e = 0; e < NEXP; e++) {
    int start = so[e] + sc[e], end = so[e + 1];
    for (int i = start + tid; i < end; i += blockDim.x) tok[i] = 0;
  }
}

__global__ void k_scatter(const int* __restrict__ idx, int stride,
                          int* __restrict__ off2, int* __restrict__ tok,
                          int* __restrict__ pos) {
  int r = blockIdx.x * blockDim.x + threadIdx.x;
  if (r >= NK) return;
  int e = idx[r * stride];
  e = min(max(e, 0), NEXP - 1);
  int p = atomicAdd(&off2[e], 1);
  tok[p] = r >> 1;
  pos[r] = p;
}

// ---- gather + fp32->bf16: Xg[p][:] = bf16(x[tok[p]][:]) ----
__global__ void k_gather(const float* __restrict__ x, const int* __restrict__ tok,
                         const int* __restrict__ offp, bf16* __restrict__ xg) {
  int rows = offp[NEXP];
  int chunks = rows * (DDIM / 8);
  int stride = gridDim.x * blockDim.x;
  for (int i = blockIdx.x * blockDim.x + threadIdx.x; i < chunks; i += stride) {
    int p = i >> 7;            // DDIM/8 = 128
    int c = i & 127;
    int r = tok[p];
    float4 a = ((const float4*)x)[((size_t)r * DDIM + c * 8) / 4];
    float4 b = ((const float4*)x)[((size_t)r * DDIM + c * 8) / 4 + 1];
    union { bf16 h[8]; uint4 v; } u;
    u.h[0] = __float2bfloat16(a.x); u.h[1] = __float2bfloat16(a.y);
    u.h[2] = __float2bfloat16(a.z); u.h[3] = __float2bfloat16(a.w);
    u.h[4] = __float2bfloat16(b.x); u.h[5] = __float2bfloat16(b.y);
    u.h[6] = __float2bfloat16(b.z); u.h[7] = __float2bfloat16(b.w);
    *(uint4*)&xg[(size_t)p * DDIM + c * 8] = u.v;
  }
}

// [E][R][C] fp32 -> [E][C][R] bf16. Tile 32R x 64C; 16B stores.
__global__ void k_transpose(const float* __restrict__ in, bf16* __restrict__ out,
                            int R, int C) {
  __shared__ float t[32][65];
  size_t ebase = (size_t)blockIdx.z * R * C;
  int r0 = blockIdx.y * 32, c0 = blockIdx.x * 64;
  int tid = threadIdx.x;
  {
    int lr = tid >> 3, lc = (tid & 7) * 8;
    const float4* src = (const float4*)&in[ebase + (size_t)(r0 + lr) * C + c0 + lc];
    float4 a = src[0], b = src[1];
    t[lr][lc + 0] = a.x; t[lr][lc + 1] = a.y; t[lr][lc + 2] = a.z; t[lr][lc + 3] = a.w;
    t[lr][lc + 4] = b.x; t[lr][lc + 5] = b.y; t[lr][lc + 6] = b.z; t[lr][lc + 7] = b.w;
  }
  __syncthreads();
  {
    int sc = tid >> 2, sr = (tid & 3) * 8;
    union { bf16 h[8]; uint4 v; } u;
#pragma unroll
    for (int j = 0; j < 8; j++) u.h[j] = __float2bfloat16(t[sr + j][sc]);
    *(uint4*)&out[ebase + (size_t)(c0 + sc) * R + r0 + sr] = u.v;
  }
}

// ---- grouped GEMM: 128x128 tile, BK=32, 4 waves (2x2), dbuf 32KB, 4 blk/CU ----
// MODE 0: Xg @ W1t -> hbuf bf16 (+bias, ReLU), slice-local rows.
// MODE 1: hbuf @ W2t -> ybuf bf16 (+bias), global rows.
template<int MODE>
__global__ __launch_bounds__(256, 4) void k_gemm(
    const bf16* __restrict__ A, const bf16* __restrict__ Bt,
    const float* __restrict__ bias, const int* __restrict__ texp,
    int tile_base, void* __restrict__ Cout)
{
  constexpr int KT   = MODE ? HDIM : DDIM;   // 4096 : 1024
  constexpr int NCOL = MODE ? DDIM : HDIM;
  constexpr int GX   = NCOL / 128;           // 8 : 32
  constexpr int NT   = KT / BK;              // 128 : 32
  constexpr int TILB = 128 * BK * 2;         // 8 KB per operand tile

  // bijective XCD-aware swizzle (m204)
  int nwg = gridDim.x, orig = blockIdx.x;
  int q8 = nwg >> 3, r8 = nwg & 7;
  int xcd = orig & 7, jj0 = orig >> 3;
  int w = (xcd < r8 ? xcd * (q8 + 1) : r8 * (q8 + 1) + (xcd - r8) * q8) + jj0;
  int tn = w % GX;
  int tmr = w / GX;
  int tm = tile_base + tmr;
  int e = texp[tm];
  if (e < 0) return;

  int tid = threadIdx.x, lane = tid & 63, wid = tid >> 6;
  int wm = wid >> 1, wn = wid & 1;           // 2M x 2N waves, 64x64 each
  int lr = lane & 15, kg = lane >> 4;

  __shared__ __align__(16) char lds[2 * 2 * TILB];   // 32 KiB

  // staging offsets (elements); source-side chunk swizzle c ^= (row>>1)&3
  int arow0 = (MODE ? tmr : tm) * BM;
  unsigned aoff[2], boff[2];
#pragma unroll
  for (int it = 0; it < 2; ++it) {
    int idx = it * 256 + tid, row = idx >> 2, c = idx & 3;
    int ch = c ^ ((row >> 1) & 3);
    aoff[it] = (unsigned)((arow0 + row) * KT + ch * 8);
    boff[it] = (unsigned)((e * NCOL + tn * 128 + row) * KT + ch * 8);
  }

  auto stage = [&](int kt, int par) {
    char* base = lds + par * (2 * TILB);
#pragma unroll
    for (int it = 0; it < 2; ++it)
      gload16(A + aoff[it] + kt * BK, base + it * 4096 + tid * 16);
#pragma unroll
    for (int it = 0; it < 2; ++it)
      gload16(Bt + boff[it] + kt * BK, base + TILB + it * 4096 + tid * 16);
  };

  f32x4 acc[4][4];
#pragma unroll
  for (int i = 0; i < 4; i++)
#pragma unroll
    for (int j = 0; j < 4; j++) acc[i][j] = (f32x4){0.f, 0.f, 0.f, 0.f};

  // prologue
  stage(0, 0);
  __syncthreads();

#pragma unroll 1
  for (int kt = 0; kt < NT; ++kt) {
    int par = kt & 1;
    const bf16* As = (const bf16*)(lds + par * (2 * TILB));
    const bf16* Bs = As + 128 * BK;

    bf16x8 av[4], bv[4];
#pragma unroll
    for (int mi = 0; mi < 4; ++mi) {
      int m = wm * 64 + mi * 16 + lr;
      int slot = kg ^ ((m >> 1) & 3);
      av[mi] = *(const bf16x8*)&As[m * BK + slot * 8];
    }
#pragma unroll
    for (int ni = 0; ni < 4; ++ni) {
      int n = wn * 64 + ni * 16 + lr;
      int slot = kg ^ ((n >> 1) & 3);
      bv[ni] = *(const bf16x8*)&Bs[n * BK + slot * 8];
    }

    if (kt + 1 < NT) stage(kt + 1, par ^ 1);

#pragma unroll
    for (int mi = 0; mi < 4; ++mi)
#pragma unroll
      for (int ni = 0; ni < 4; ++ni)
        acc[mi][ni] = __builtin_amdgcn_mfma_f32_16x16x32_bf16(
            av[mi], bv[ni], acc[mi][ni], 0, 0, 0);

    __syncthreads();   // drains vmcnt (prefetch kt+1) + lgkm, then barrier
  }

  // epilogue (C/D map m89)
  const float* be = bias + (size_t)e * NCOL;
  int crow0 = (MODE ? tm : tmr) * BM;
#pragma unroll
  for (int ni = 0; ni < 4; ++ni) {
    int n = tn * 128 + wn * 64 + ni * 16 + lr;
    float bvv = be[n];
#pragma unroll
    for (int mi = 0; mi < 4; ++mi) {
#pragma unroll
      for (int j = 0; j < 4; j++) {
        int mrow = wm * 64 + mi * 16 + kg * 4 + j;
        float v = acc[mi][ni][j] + bvv;
        if (MODE == 0) v = fmaxf(v, 0.f);
        ((bf16*)Cout)[(size_t)(crow0 + mrow) * NCOL + n] = __float2bfloat16(v);
      }
    }
  }
}

// ---- combine (bf16 y) ----
__global__ void k_combine(const bf16* __restrict__ y, const float* __restrict__ prob,
                          const int* __restrict__ pos, float* __restrict__ out) {
  int gid = blockIdx.x * blockDim.x + threadIdx.x;  // over N*D/8
  if (gid >= N_TOK * DDIM / 8) return;
  int n = gid >> 7;          // DDIM/8 = 128
  int d8 = gid & 127;
  int r0 = pos[2 * n], r1 = pos[2 * n + 1];
  float p0 = prob[2 * n], p1 = prob[2 * n + 1];
  uint4 a = *(const uint4*)&y[(size_t)r0 * DDIM + d8 * 8];
  uint4 b = *(const uint4*)&y[(size_t)r1 * DDIM + d8 * 8];
  const unsigned short* ah = (const unsigned short*)&a;
  const unsigned short* bh = (const unsigned short*)&b;
  float o[8];
#pragma unroll
  for (int k = 0; k < 8; k++) {
    float fa = __uint_as_float((unsigned)ah[k] << 16);
    float fb = __uint_as_float((unsigned)bh[k] << 16);
    o[k] = p0 * fa + p1 * fb;
  }
  float4* op = (float4*)&out[(size_t)n * DDIM + d8 * 8];
  op[0] = (float4){o[0], o[1], o[2], o[3]};
  op[1] = (float4){o[4], o[5], o[6], o[7]};
  if (gid == 0) out[(size_t)N_TOK * DDIM] = 0.f;   // total_loss
}

extern "C" void kernel_launch(void* const* d_in, const int* in_sizes, int n_in,
                              void* d_out, int out_size, void* d_ws, size_t ws_size,
                              hipStream_t stream) {
  const float* x    = (const float*)d_in[0];
  const float* prob = (const float*)d_in[1];
  const int*   idx  = (const int*)d_in[2];
  const float* W1   = (const float*)d_in[3];
  const float* b1   = (const float*)d_in[4];
  const float* W2   = (const float*)d_in[5];
  const float* b2   = (const float*)d_in[6];
  float* out = (float*)d_out;
  int stride = (in_sizes[2] == NK) ? 1 : 2;   // int32 vs int64 (LE low word)

  char* ws = (char*)d_ws;
  size_t cur = 0;
  auto alloc = [&](size_t bytes) -> void* {
    cur = (cur + 255) & ~(size_t)255;
    void* p = ws + cur; cur += bytes; return p;
  };
  int* cnt   = (int*)alloc(NEXP * 4);
  int* offp  = (int*)alloc((NEXP + 1) * 4);
  int* off2  = (int*)alloc(NEXP * 4);
  int* texp  = (int*)alloc(MAXT * 4);
  int* tok   = (int*)alloc((size_t)MAXT * BM * 4);
  int* pos   = (int*)alloc((size_t)NK * 4);
  bf16* Xg   = (bf16*)alloc((size_t)MAXT * BM * DDIM * 2);
  bf16* W1t  = (bf16*)alloc((size_t)NEXP * HDIM * DDIM * 2);
  bf16* W2t  = (bf16*)alloc((size_t)NEXP * DDIM * HDIM * 2);
  bf16* ybuf = (bf16*)alloc((size_t)MAXT * BM * DDIM * 2);
  cur = (cur + 255) & ~(size_t)255;
  size_t h_off = cur;
  size_t h_avail = ws_size > h_off ? ws_size - h_off : 0;
  long long ts_ll = (long long)(h_avail / ((size_t)BM * HDIM * 2));
  int ts = (int)(ts_ll < 1 ? 1 : (ts_ll > MAXT ? MAXT : ts_ll));
  bf16* hbuf = (bf16*)(ws + h_off);

  hipMemsetAsync(cnt, 0, NEXP * 4, stream);
  k_count<<<(NK + 255) / 256, 256, 0, stream>>>(idx, stride, cnt);
  k_scan<<<1, 256, 0, stream>>>(cnt, offp, off2, texp, tok);
  k_scatter<<<(NK + 255) / 256, 256, 0, stream>>>(idx, stride, off2, tok, pos);
  k_gather<<<2048, 256, 0, stream>>>(x, tok, offp, Xg);
  k_transpose<<<dim3(HDIM / 64, DDIM / 32, NEXP), 256, 0, stream>>>(W1, W1t, DDIM, HDIM);
  k_transpose<<<dim3(DDIM / 64, HDIM / 32, NEXP), 256, 0, stream>>>(W2, W2t, HDIM, DDIM);

  for (int base = 0; base < MAXT; base += ts) {
    int cnt_t = (MAXT - base < ts) ? (MAXT - base) : ts;
    k_gemm<0><<<dim3(cnt_t * (HDIM / 128)), 256, 0, stream>>>(
        Xg, W1t, b1, texp, base, (void*)hbuf);
    k_gemm<1><<<dim3(cnt_t * (DDIM / 128)), 256, 0, stream>>>(
        hbuf, W2t, b2, texp, base, (void*)ybuf);
  }
  k_combine<<<(N_TOK * DDIM / 8 + 255) / 256, 256, 0, stream>>>(ybuf, prob, pos, out);
}

// Round 9
// 629.574 us; speedup vs baseline: 3.6310x; 1.0005x over previous
//
#include <hip/hip_runtime.h>
#include <hip/hip_bf16.h>

#define N_TOK 8192
#define DDIM 1024
#define HDIM 4096
#define NEXP 8
#define TOPK 2
#define NK (N_TOK*TOPK)
#define BM 256
#define BK 32
#define MAXT 72    // 16384/256 + 8 pad tiles

typedef __hip_bfloat16 bf16;
typedef __attribute__((ext_vector_type(8))) short bf16x8;
typedef __attribute__((ext_vector_type(4))) float f32x4;

__device__ __forceinline__ void gload16(const void* g, void* lds) {
  auto l = (__attribute__((address_space(3))) unsigned int*)(unsigned int)(unsigned long long)lds;
  auto gg = (const __attribute__((address_space(1))) unsigned int*)(unsigned long long)g;
  __builtin_amdgcn_global_load_lds(gg, l, 16, 0, 0);
}

// ---- router ----
__global__ void k_count(const int* __restrict__ idx, int stride,
                        int* __restrict__ cnt) {
  int r = blockIdx.x * blockDim.x + threadIdx.x;
  if (r >= NK) return;
  int e = idx[r * stride];
  e = min(max(e, 0), NEXP - 1);
  atomicAdd(&cnt[e], 1);
}

__global__ void k_scan(const int* __restrict__ cnt, int* __restrict__ offp,
                       int* __restrict__ off2, int* __restrict__ texp,
                       int* __restrict__ tok) {
  __shared__ int so[NEXP + 1], sc[NEXP];
  int tid = threadIdx.x;
  if (tid == 0) {
    int cum = 0;
    for (int e = 0; e < NEXP; e++) {
      so[e] = cum; sc[e] = cnt[e];
      cum += ((cnt[e] + BM - 1) / BM) * BM;
    }
    so[NEXP] = cum;
    for (int e = 0; e <= NEXP; e++) offp[e] = so[e];
  }
  __syncthreads();
  if (tid < NEXP) off2[tid] = so[tid];
  int total_tiles = so[NEXP] / BM;
  for (int t = tid; t < MAXT; t += blockDim.x) {
    int e = -1;
    if (t < total_tiles) {
      for (int q = 0; q < NEXP; q++)
        if (t * BM >= so[q] && t * BM < so[q + 1]) e = q;
    }
    texp[t] = e;
  }
  for (int e = 0; e < NEXP; e++) {
    int start = so[e] + sc[e], end = so[e + 1];
    for (int i = start + tid; i < end; i += blockDim.x) tok[i] = 0;
  }
}

__global__ void k_scatter(const int* __restrict__ idx, int stride,
                          int* __restrict__ off2, int* __restrict__ tok,
                          int* __restrict__ pos) {
  int r = blockIdx.x * blockDim.x + threadIdx.x;
  if (r >= NK) return;
  int e = idx[r * stride];
  e = min(max(e, 0), NEXP - 1);
  int p = atomicAdd(&off2[e], 1);
  tok[p] = r >> 1;
  pos[r] = p;
}

// ---- fp32 -> bf16 convert of X ----
__global__ void k_cvt_x(const float* __restrict__ x, bf16* __restrict__ xb) {
  int i = blockIdx.x * blockDim.x + threadIdx.x;   // over N*D/8
  if (i >= N_TOK * DDIM / 8) return;
  float4 a = ((const float4*)x)[(size_t)i * 2];
  float4 b = ((const float4*)x)[(size_t)i * 2 + 1];
  union { bf16 h[8]; uint4 v; } u;
  u.h[0] = __float2bfloat16(a.x); u.h[1] = __float2bfloat16(a.y);
  u.h[2] = __float2bfloat16(a.z); u.h[3] = __float2bfloat16(a.w);
  u.h[4] = __float2bfloat16(b.x); u.h[5] = __float2bfloat16(b.y);
  u.h[6] = __float2bfloat16(b.z); u.h[7] = __float2bfloat16(b.w);
  *(uint4*)&xb[(size_t)i * 8] = u.v;
}

// [E][R][C] fp32 -> [E][C][R] bf16. Tile 32R x 64C; 16B stores.
__global__ void k_transpose(const float* __restrict__ in, bf16* __restrict__ out,
                            int R, int C) {
  __shared__ float t[32][65];
  size_t ebase = (size_t)blockIdx.z * R * C;
  int r0 = blockIdx.y * 32, c0 = blockIdx.x * 64;
  int tid = threadIdx.x;
  {
    int lr = tid >> 3, lc = (tid & 7) * 8;
    const float4* src = (const float4*)&in[ebase + (size_t)(r0 + lr) * C + c0 + lc];
    float4 a = src[0], b = src[1];
    t[lr][lc + 0] = a.x; t[lr][lc + 1] = a.y; t[lr][lc + 2] = a.z; t[lr][lc + 3] = a.w;
    t[lr][lc + 4] = b.x; t[lr][lc + 5] = b.y; t[lr][lc + 6] = b.z; t[lr][lc + 7] = b.w;
  }
  __syncthreads();
  {
    int sc = tid >> 2, sr = (tid & 3) * 8;
    union { bf16 h[8]; uint4 v; } u;
#pragma unroll
    for (int j = 0; j < 8; j++) u.h[j] = __float2bfloat16(t[sr + j][sc]);
    *(uint4*)&out[ebase + (size_t)(c0 + sc) * R + r0 + sr] = u.v;
  }
}

// ---- grouped GEMM: 256x256 tile, BK=32, 8 waves (2Mx4N, 128x64/wave),
//      3-buffer LDS pipeline, ONE barrier + ONE counted vmcnt per K-step ----
// MODE 0: Xb(gathered via tok) @ W1t -> hbuf bf16 (+bias, ReLU), slice rows.
// MODE 1: hbuf @ W2t -> ybuf bf16 (+bias), global rows.
template<int MODE>
__global__ __launch_bounds__(512, 2) void k_gemm(
    const bf16* __restrict__ A, const bf16* __restrict__ Bt,
    const float* __restrict__ bias, const int* __restrict__ texp,
    const int* __restrict__ tok, int tile_base, void* __restrict__ Cout)
{
  constexpr int KT   = MODE ? HDIM : DDIM;   // 4096 : 1024
  constexpr int NCOL = MODE ? DDIM : HDIM;
  constexpr int GX   = NCOL / 256;           // 4 : 16
  constexpr int NT   = KT / BK;              // 128 : 32
  constexpr int BUFB = 512 * BK * 2;         // 32 KB per buffer (A 16K + B 16K)

  // bijective XCD-aware swizzle (m204)
  int nwg = gridDim.x, orig = blockIdx.x;
  int q8 = nwg >> 3, r8 = nwg & 7;
  int xcd = orig & 7, jj0 = orig >> 3;
  int w = (xcd < r8 ? xcd * (q8 + 1) : r8 * (q8 + 1) + (xcd - r8) * q8) + jj0;
  int tn = w % GX;
  int tmr = w / GX;
  int tm = tile_base + tmr;
  int e = texp[tm];
  if (e < 0) return;

  int tid = threadIdx.x, lane = tid & 63, wid = tid >> 6;
  int wm = wid >> 2, wn = wid & 3;           // 2M x 4N waves, 128x64 each
  int lr = lane & 15, kg = lane >> 4;

  __shared__ __align__(16) char lds[3 * BUFB];   // 96 KiB

  // staging source offsets (elements); source-side chunk swizzle c ^= (row>>1)&3
  unsigned aoff[2], boff[2];
#pragma unroll
  for (int it = 0; it < 2; ++it) {
    int idx = it * 512 + tid, row = idx >> 2, c = idx & 3;
    int ch = c ^ ((row >> 1) & 3);
    int arow = MODE ? (tmr * BM + row) : tok[tm * BM + row];
    aoff[it] = (unsigned)(arow * KT + ch * 8);
    boff[it] = (unsigned)((e * NCOL + tn * 256 + row) * KT + ch * 8);
  }

  auto stage = [&](int kt, int buf) {
    char* base = lds + buf * BUFB;
#pragma unroll
    for (int it = 0; it < 2; ++it)
      gload16(A + aoff[it] + kt * BK, base + (it * 512 + tid) * 16);
#pragma unroll
    for (int it = 0; it < 2; ++it)
      gload16(Bt + boff[it] + kt * BK, base + 16384 + (it * 512 + tid) * 16);
  };

  f32x4 acc[8][4];
#pragma unroll
  for (int i = 0; i < 8; i++)
#pragma unroll
    for (int j = 0; j < 4; j++) acc[i][j] = (f32x4){0.f, 0.f, 0.f, 0.f};

  // prologue: two tiles in flight, publish tile 0
  stage(0, 0);
  stage(1, 1);
  asm volatile("s_waitcnt vmcnt(4)" ::: "memory");   // tile 0 landed
  __builtin_amdgcn_s_barrier();

#pragma unroll 1
  for (int kt = 0; kt < NT; ++kt) {
    const char* base = lds + (kt % 3) * BUFB;

    bf16x8 av[8], bv[4];
#pragma unroll
    for (int mi = 0; mi < 8; ++mi) {
      int m = wm * 128 + mi * 16 + lr;
      int slot = kg ^ ((m >> 1) & 3);
      av[mi] = *(const bf16x8*)(base + m * 64 + slot * 16);
    }
#pragma unroll
    for (int ni = 0; ni < 4; ++ni) {
      int n = wn * 64 + ni * 16 + lr;
      int slot = kg ^ ((n >> 1) & 3);
      bv[ni] = *(const bf16x8*)(base + 16384 + n * 64 + slot * 16);
    }

    if (kt + 2 < NT) stage(kt + 2, (kt + 2) % 3);   // overwrites buf of tile kt-1 (reads done)

#pragma unroll
    for (int mi = 0; mi < 8; ++mi)
#pragma unroll
      for (int ni = 0; ni < 4; ++ni)
        acc[mi][ni] = __builtin_amdgcn_mfma_f32_16x16x32_bf16(
            av[mi], bv[ni], acc[mi][ni], 0, 0, 0);

    if (kt + 1 < NT) {
      if (kt + 2 < NT) asm volatile("s_waitcnt vmcnt(4)" ::: "memory"); // tile kt+1 landed, kt+2 stays in flight
      else             asm volatile("s_waitcnt vmcnt(0)" ::: "memory");
      __builtin_amdgcn_s_barrier();
    }
  }

  // epilogue (C/D map m89)
  const float* be = bias + (size_t)e * NCOL;
  int crow0 = (MODE ? tm : tmr) * BM;
#pragma unroll
  for (int ni = 0; ni < 4; ++ni) {
    int n = tn * 256 + wn * 64 + ni * 16 + lr;
    float bvv = be[n];
#pragma unroll
    for (int mi = 0; mi < 8; ++mi) {
#pragma unroll
      for (int j = 0; j < 4; j++) {
        int mrow = wm * 128 + mi * 16 + kg * 4 + j;
        float v = acc[mi][ni][j] + bvv;
        if (MODE == 0) v = fmaxf(v, 0.f);
        ((bf16*)Cout)[(size_t)(crow0 + mrow) * NCOL + n] = __float2bfloat16(v);
      }
    }
  }
}

// ---- combine (bf16 y) ----
__global__ void k_combine(const bf16* __restrict__ y, const float* __restrict__ prob,
                          const int* __restrict__ pos, float* __restrict__ out) {
  int gid = blockIdx.x * blockDim.x + threadIdx.x;  // over N*D/8
  if (gid >= N_TOK * DDIM / 8) return;
  int n = gid >> 7;          // DDIM/8 = 128
  int d8 = gid & 127;
  int r0 = pos[2 * n], r1 = pos[2 * n + 1];
  float p0 = prob[2 * n], p1 = prob[2 * n + 1];
  uint4 a = *(const uint4*)&y[(size_t)r0 * DDIM + d8 * 8];
  uint4 b = *(const uint4*)&y[(size_t)r1 * DDIM + d8 * 8];
  const unsigned short* ah = (const unsigned short*)&a;
  const unsigned short* bh = (const unsigned short*)&b;
  float o[8];
#pragma unroll
  for (int k = 0; k < 8; k++) {
    float fa = __uint_as_float((unsigned)ah[k] << 16);
    float fb = __uint_as_float((unsigned)bh[k] << 16);
    o[k] = p0 * fa + p1 * fb;
  }
  float4* op = (float4*)&out[(size_t)n * DDIM + d8 * 8];
  op[0] = (float4){o[0], o[1], o[2], o[3]};
  op[1] = (float4){o[4], o[5], o[6], o[7]};
  if (gid == 0) out[(size_t)N_TOK * DDIM] = 0.f;   // total_loss
}

extern "C" void kernel_launch(void* const* d_in, const int* in_sizes, int n_in,
                              void* d_out, int out_size, void* d_ws, size_t ws_size,
                              hipStream_t stream) {
  const float* x    = (const float*)d_in[0];
  const float* prob = (const float*)d_in[1];
  const int*   idx  = (const int*)d_in[2];
  const float* W1   = (const float*)d_in[3];
  const float* b1   = (const float*)d_in[4];
  const float* W2   = (const float*)d_in[5];
  const float* b2   = (const float*)d_in[6];
  float* out = (float*)d_out;
  int stride = (in_sizes[2] == NK) ? 1 : 2;   // int32 vs int64 (LE low word)

  char* ws = (char*)d_ws;
  size_t cur = 0;
  auto alloc = [&](size_t bytes) -> void* {
    cur = (cur + 255) & ~(size_t)255;
    void* p = ws + cur; cur += bytes; return p;
  };
  int* cnt   = (int*)alloc(NEXP * 4);
  int* offp  = (int*)alloc((NEXP + 1) * 4);
  int* off2  = (int*)alloc(NEXP * 4);
  int* texp  = (int*)alloc(MAXT * 4);
  int* tok   = (int*)alloc((size_t)MAXT * BM * 4);
  int* pos   = (int*)alloc((size_t)NK * 4);
  bf16* Xb   = (bf16*)alloc((size_t)N_TOK * DDIM * 2);
  bf16* W1t  = (bf16*)alloc((size_t)NEXP * HDIM * DDIM * 2);
  bf16* W2t  = (bf16*)alloc((size_t)NEXP * DDIM * HDIM * 2);
  bf16* ybuf = (bf16*)alloc((size_t)MAXT * BM * DDIM * 2);
  cur = (cur + 255) & ~(size_t)255;
  size_t h_off = cur;
  size_t h_avail = ws_size > h_off ? ws_size - h_off : 0;
  long long ts_ll = (long long)(h_avail / ((size_t)BM * HDIM * 2));
  int ts = (int)(ts_ll < 1 ? 1 : (ts_ll > MAXT ? MAXT : ts_ll));
  bf16* hbuf = (bf16*)(ws + h_off);

  hipMemsetAsync(cnt, 0, NEXP * 4, stream);
  k_count<<<(NK + 255) / 256, 256, 0, stream>>>(idx, stride, cnt);
  k_scan<<<1, 256, 0, stream>>>(cnt, offp, off2, texp, tok);
  k_scatter<<<(NK + 255) / 256, 256, 0, stream>>>(idx, stride, off2, tok, pos);
  k_cvt_x<<<(N_TOK * DDIM / 8 + 255) / 256, 256, 0, stream>>>(x, Xb);
  k_transpose<<<dim3(HDIM / 64, DDIM / 32, NEXP), 256, 0, stream>>>(W1, W1t, DDIM, HDIM);
  k_transpose<<<dim3(DDIM / 64, HDIM / 32, NEXP), 256, 0, stream>>>(W2, W2t, HDIM, DDIM);

  for (int base = 0; base < MAXT; base += ts) {
    int cnt_t = (MAXT - base < ts) ? (MAXT - base) : ts;
    k_gemm<0><<<dim3(cnt_t * (HDIM / 256)), 512, 0, stream>>>(
        Xb, W1t, b1, texp, tok, base, (void*)hbuf);
    k_gemm<1><<<dim3(cnt_t * (DDIM / 256)), 512, 0, stream>>>(
        hbuf, W2t, b2, texp, tok, base, (void*)ybuf);
  }
  k_combine<<<(N_TOK * DDIM / 8 + 255) / 256, 256, 0, stream>>>(ybuf, prob, pos, out);
}

// Round 10
// 582.537 us; speedup vs baseline: 3.9241x; 1.0807x over previous
//
#include <hip/hip_runtime.h>
#include <hip/hip_bf16.h>

#define N_TOK 8192
#define DDIM 1024
#define HDIM 4096
#define NEXP 8
#define TOPK 2
#define NK (N_TOK*TOPK)
#define BM 128
#define BK 32
#define MAXT 136   // 16384/128 + 8 pad tiles

typedef __hip_bfloat16 bf16;
typedef __attribute__((ext_vector_type(8))) short bf16x8;
typedef __attribute__((ext_vector_type(4))) float f32x4;

__device__ __forceinline__ void gload16(const void* g, void* lds) {
  auto l = (__attribute__((address_space(3))) unsigned int*)(unsigned int)(unsigned long long)lds;
  auto gg = (const __attribute__((address_space(1))) unsigned int*)(unsigned long long)g;
  __builtin_amdgcn_global_load_lds(gg, l, 16, 0, 0);
}

// ---- router ----
__global__ void k_count(const int* __restrict__ idx, int stride,
                        int* __restrict__ cnt) {
  int r = blockIdx.x * blockDim.x + threadIdx.x;
  if (r >= NK) return;
  int e = idx[r * stride];
  e = min(max(e, 0), NEXP - 1);
  atomicAdd(&cnt[e], 1);
}

__global__ void k_scan(const int* __restrict__ cnt, int* __restrict__ offp,
                       int* __restrict__ off2, int* __restrict__ texp,
                       int* __restrict__ tok) {
  __shared__ int so[NEXP + 1], sc[NEXP];
  int tid = threadIdx.x;
  if (tid == 0) {
    int cum = 0;
    for (int e = 0; e < NEXP; e++) {
      so[e] = cum; sc[e] = cnt[e];
      cum += ((cnt[e] + BM - 1) / BM) * BM;
    }
    so[NEXP] = cum;
    for (int e = 0; e <= NEXP; e++) offp[e] = so[e];
  }
  __syncthreads();
  if (tid < NEXP) off2[tid] = so[tid];
  int total_tiles = so[NEXP] / BM;
  for (int t = tid; t < MAXT; t += blockDim.x) {
    int e = -1;
    if (t < total_tiles) {
      for (int q = 0; q < NEXP; q++)
        if (t * BM >= so[q] && t * BM < so[q + 1]) e = q;
    }
    texp[t] = e;
  }
  for (int e = 0; e < NEXP; e++) {
    int start = so[e] + sc[e], end = so[e + 1];
    for (int i = start + tid; i < end; i += blockDim.x) tok[i] = 0;
  }
}

__global__ void k_scatter(const int* __restrict__ idx, int stride,
                          int* __restrict__ off2, int* __restrict__ tok,
                          int* __restrict__ pos) {
  int r = blockIdx.x * blockDim.x + threadIdx.x;
  if (r >= NK) return;
  int e = idx[r * stride];
  e = min(max(e, 0), NEXP - 1);
  int p = atomicAdd(&off2[e], 1);
  tok[p] = r >> 1;
  pos[r] = p;
}

// ---- fp32 -> bf16 convert of X ----
__global__ void k_cvt_x(const float* __restrict__ x, bf16* __restrict__ xb) {
  int i = blockIdx.x * blockDim.x + threadIdx.x;   // over N*D/8
  if (i >= N_TOK * DDIM / 8) return;
  float4 a = ((const float4*)x)[(size_t)i * 2];
  float4 b = ((const float4*)x)[(size_t)i * 2 + 1];
  union { bf16 h[8]; uint4 v; } u;
  u.h[0] = __float2bfloat16(a.x); u.h[1] = __float2bfloat16(a.y);
  u.h[2] = __float2bfloat16(a.z); u.h[3] = __float2bfloat16(a.w);
  u.h[4] = __float2bfloat16(b.x); u.h[5] = __float2bfloat16(b.y);
  u.h[6] = __float2bfloat16(b.z); u.h[7] = __float2bfloat16(b.w);
  *(uint4*)&xb[(size_t)i * 8] = u.v;
}

// [E][R][C] fp32 -> [E][C][R] bf16. Tile 32R x 64C; 16B stores.
__global__ void k_transpose(const float* __restrict__ in, bf16* __restrict__ out,
                            int R, int C) {
  __shared__ float t[32][65];
  size_t ebase = (size_t)blockIdx.z * R * C;
  int r0 = blockIdx.y * 32, c0 = blockIdx.x * 64;
  int tid = threadIdx.x;
  {
    int lr = tid >> 3, lc = (tid & 7) * 8;
    const float4* src = (const float4*)&in[ebase + (size_t)(r0 + lr) * C + c0 + lc];
    float4 a = src[0], b = src[1];
    t[lr][lc + 0] = a.x; t[lr][lc + 1] = a.y; t[lr][lc + 2] = a.z; t[lr][lc + 3] = a.w;
    t[lr][lc + 4] = b.x; t[lr][lc + 5] = b.y; t[lr][lc + 6] = b.z; t[lr][lc + 7] = b.w;
  }
  __syncthreads();
  {
    int sc = tid >> 2, sr = (tid & 3) * 8;
    union { bf16 h[8]; uint4 v; } u;
#pragma unroll
    for (int j = 0; j < 8; j++) u.h[j] = __float2bfloat16(t[sr + j][sc]);
    *(uint4*)&out[ebase + (size_t)(c0 + sc) * R + r0 + sr] = u.v;
  }
}

// ---- grouped GEMM: 128x256 tile, BK=32, 8 waves (2Mx4N, 64x64/wave),
//      3-buffer LDS (72 KB -> 2 blocks/CU), counted vmcnt(3), 1 barrier/step ----
// MODE 0: Xb(gathered via tok) @ W1t -> hbuf bf16 (+bias, ReLU), slice rows.
// MODE 1: hbuf @ W2t -> ybuf bf16 (+bias), global rows.
template<int MODE>
__global__ __launch_bounds__(512, 4) void k_gemm(
    const bf16* __restrict__ A, const bf16* __restrict__ Bt,
    const float* __restrict__ bias, const int* __restrict__ texp,
    const int* __restrict__ tok, int tile_base, void* __restrict__ Cout)
{
  constexpr int KT   = MODE ? HDIM : DDIM;   // 4096 : 1024
  constexpr int NCOL = MODE ? DDIM : HDIM;
  constexpr int BN   = 256;
  constexpr int GX   = NCOL / BN;            // 4 : 16
  constexpr int NT   = KT / BK;              // 128 : 32
  constexpr int BUFB = (BM + BN) * BK * 2;   // 24 KB per buffer

  // bijective XCD-aware swizzle (m204)
  int nwg = gridDim.x, orig = blockIdx.x;
  int q8 = nwg >> 3, r8 = nwg & 7;
  int xcd = orig & 7, jj0 = orig >> 3;
  int w = (xcd < r8 ? xcd * (q8 + 1) : r8 * (q8 + 1) + (xcd - r8) * q8) + jj0;
  int tn = w % GX;
  int tmr = w / GX;
  int tm = tile_base + tmr;
  int e = texp[tm];
  if (e < 0) return;

  int tid = threadIdx.x, lane = tid & 63, wid = tid >> 6;
  int wm = wid >> 2, wn = wid & 3;           // 2M x 4N waves, 64x64 each
  int lr = lane & 15, kg = lane >> 4;

  __shared__ __align__(16) char lds[3 * BUFB];   // 72 KiB

  // staging source offsets (elements); source chunk swizzle c ^= (row>>1)&3
  // it=0: A rows 0..127 (4 thr/row); it=1,2: B rows 0..255.
  unsigned goff[3];
  {
    int row = tid >> 2, c = tid & 3;
    int ch = c ^ ((row >> 1) & 3);
    int arow = MODE ? (tmr * BM + row) : tok[tm * BM + row];
    goff[0] = (unsigned)(arow * KT + ch * 8);
    goff[1] = (unsigned)((e * NCOL + tn * BN + row) * KT + ch * 8);
    goff[2] = (unsigned)((e * NCOL + tn * BN + 128 + row) * KT + ch * 8);
  }

  auto stage = [&](int kt, int buf) {
    char* base = lds + buf * BUFB;
    gload16(A + goff[0] + kt * BK, base + tid * 16);
    gload16(Bt + goff[1] + kt * BK, base + 8192 + tid * 16);
    gload16(Bt + goff[2] + kt * BK, base + 16384 + tid * 16);
  };

  f32x4 acc[4][4];
#pragma unroll
  for (int i = 0; i < 4; i++)
#pragma unroll
    for (int j = 0; j < 4; j++) acc[i][j] = (f32x4){0.f, 0.f, 0.f, 0.f};

  // prologue: tiles 0,1 in flight; publish tile 0
  stage(0, 0);
  stage(1, 1);
  asm volatile("s_waitcnt vmcnt(3)" ::: "memory");
  __builtin_amdgcn_s_barrier();

#pragma unroll 1
  for (int kt = 0; kt < NT; ++kt) {
    if (kt + 2 < NT) stage(kt + 2, (kt + 2) % 3);   // buf of tile kt-1: reads done

    const char* base = lds + (kt % 3) * BUFB;
    bf16x8 av[4], bv[4];
#pragma unroll
    for (int mi = 0; mi < 4; ++mi) {
      int m = wm * 64 + mi * 16 + lr;
      int slot = kg ^ ((m >> 1) & 3);
      av[mi] = *(const bf16x8*)(base + m * 64 + slot * 16);
    }
#pragma unroll
    for (int ni = 0; ni < 4; ++ni) {
      int n = wn * 64 + ni * 16 + lr;
      int slot = kg ^ ((n >> 1) & 3);
      bv[ni] = *(const bf16x8*)(base + 8192 + n * 64 + slot * 16);
    }

#pragma unroll
    for (int mi = 0; mi < 4; ++mi)
#pragma unroll
      for (int ni = 0; ni < 4; ++ni)
        acc[mi][ni] = __builtin_amdgcn_mfma_f32_16x16x32_bf16(
            av[mi], bv[ni], acc[mi][ni], 0, 0, 0);

    if (kt + 1 < NT) {
      if (kt + 2 < NT) asm volatile("s_waitcnt vmcnt(3)" ::: "memory"); // kt+1 landed, kt+2 in flight
      else             asm volatile("s_waitcnt vmcnt(0)" ::: "memory");
      __builtin_amdgcn_s_barrier();
    }
  }

  // epilogue (C/D map m89)
  const float* be = bias + (size_t)e * NCOL;
  int crow0 = (MODE ? tm : tmr) * BM;
#pragma unroll
  for (int ni = 0; ni < 4; ++ni) {
    int n = tn * BN + wn * 64 + ni * 16 + lr;
    float bvv = be[n];
#pragma unroll
    for (int mi = 0; mi < 4; ++mi) {
#pragma unroll
      for (int j = 0; j < 4; j++) {
        int mrow = wm * 64 + mi * 16 + kg * 4 + j;
        float v = acc[mi][ni][j] + bvv;
        if (MODE == 0) v = fmaxf(v, 0.f);
        ((bf16*)Cout)[(size_t)(crow0 + mrow) * NCOL + n] = __float2bfloat16(v);
      }
    }
  }
}

// ---- combine (bf16 y) ----
__global__ void k_combine(const bf16* __restrict__ y, const float* __restrict__ prob,
                          const int* __restrict__ pos, float* __restrict__ out) {
  int gid = blockIdx.x * blockDim.x + threadIdx.x;  // over N*D/8
  if (gid >= N_TOK * DDIM / 8) return;
  int n = gid >> 7;          // DDIM/8 = 128
  int d8 = gid & 127;
  int r0 = pos[2 * n], r1 = pos[2 * n + 1];
  float p0 = prob[2 * n], p1 = prob[2 * n + 1];
  uint4 a = *(const uint4*)&y[(size_t)r0 * DDIM + d8 * 8];
  uint4 b = *(const uint4*)&y[(size_t)r1 * DDIM + d8 * 8];
  const unsigned short* ah = (const unsigned short*)&a;
  const unsigned short* bh = (const unsigned short*)&b;
  float o[8];
#pragma unroll
  for (int k = 0; k < 8; k++) {
    float fa = __uint_as_float((unsigned)ah[k] << 16);
    float fb = __uint_as_float((unsigned)bh[k] << 16);
    o[k] = p0 * fa + p1 * fb;
  }
  float4* op = (float4*)&out[(size_t)n * DDIM + d8 * 8];
  op[0] = (float4){o[0], o[1], o[2], o[3]};
  op[1] = (float4){o[4], o[5], o[6], o[7]};
  if (gid == 0) out[(size_t)N_TOK * DDIM] = 0.f;   // total_loss
}

extern "C" void kernel_launch(void* const* d_in, const int* in_sizes, int n_in,
                              void* d_out, int out_size, void* d_ws, size_t ws_size,
                              hipStream_t stream) {
  const float* x    = (const float*)d_in[0];
  const float* prob = (const float*)d_in[1];
  const int*   idx  = (const int*)d_in[2];
  const float* W1   = (const float*)d_in[3];
  const float* b1   = (const float*)d_in[4];
  const float* W2   = (const float*)d_in[5];
  const float* b2   = (const float*)d_in[6];
  float* out = (float*)d_out;
  int stride = (in_sizes[2] == NK) ? 1 : 2;   // int32 vs int64 (LE low word)

  char* ws = (char*)d_ws;
  size_t cur = 0;
  auto alloc = [&](size_t bytes) -> void* {
    cur = (cur + 255) & ~(size_t)255;
    void* p = ws + cur; cur += bytes; return p;
  };
  int* cnt   = (int*)alloc(NEXP * 4);
  int* offp  = (int*)alloc((NEXP + 1) * 4);
  int* off2  = (int*)alloc(NEXP * 4);
  int* texp  = (int*)alloc(MAXT * 4);
  int* tok   = (int*)alloc((size_t)MAXT * BM * 4);
  int* pos   = (int*)alloc((size_t)NK * 4);
  bf16* Xb   = (bf16*)alloc((size_t)N_TOK * DDIM * 2);
  bf16* W1t  = (bf16*)alloc((size_t)NEXP * HDIM * DDIM * 2);
  bf16* W2t  = (bf16*)alloc((size_t)NEXP * DDIM * HDIM * 2);
  bf16* ybuf = (bf16*)alloc((size_t)MAXT * BM * DDIM * 2);
  cur = (cur + 255) & ~(size_t)255;
  size_t h_off = cur;
  size_t h_avail = ws_size > h_off ? ws_size - h_off : 0;
  long long ts_ll = (long long)(h_avail / ((size_t)BM * HDIM * 2));
  int ts = (int)(ts_ll < 1 ? 1 : (ts_ll > MAXT ? MAXT : ts_ll));
  bf16* hbuf = (bf16*)(ws + h_off);

  hipMemsetAsync(cnt, 0, NEXP * 4, stream);
  k_count<<<(NK + 255) / 256, 256, 0, stream>>>(idx, stride, cnt);
  k_scan<<<1, 256, 0, stream>>>(cnt, offp, off2, texp, tok);
  k_scatter<<<(NK + 255) / 256, 256, 0, stream>>>(idx, stride, off2, tok, pos);
  k_cvt_x<<<(N_TOK * DDIM / 8 + 255) / 256, 256, 0, stream>>>(x, Xb);
  k_transpose<<<dim3(HDIM / 64, DDIM / 32, NEXP), 256, 0, stream>>>(W1, W1t, DDIM, HDIM);
  k_transpose<<<dim3(DDIM / 64, HDIM / 32, NEXP), 256, 0, stream>>>(W2, W2t, HDIM, DDIM);

  for (int base = 0; base < MAXT; base += ts) {
    int cnt_t = (MAXT - base < ts) ? (MAXT - base) : ts;
    k_gemm<0><<<dim3(cnt_t * (HDIM / 256)), 512, 0, stream>>>(
        Xb, W1t, b1, texp, tok, base, (void*)hbuf);
    k_gemm<1><<<dim3(cnt_t * (DDIM / 256)), 512, 0, stream>>>(
        hbuf, W2t, b2, texp, tok, base, (void*)ybuf);
  }
  k_combine<<<(N_TOK * DDIM / 8 + 255) / 256, 256, 0, stream>>>(ybuf, prob, pos, out);
}